// Round 11
// baseline (567.455 us; speedup 1.0000x reference)
//
#include <hip/hip_runtime.h>
#include <hip/hip_fp16.h>
#include <math.h>

#define NN 50000
#define EE 800000
#define DD 512
#define HH 256
#define KK 16
#define NB_SCAN 196  // ceil(NN/256)

typedef _Float16 half8_t __attribute__((ext_vector_type(8)));
typedef float f32x4 __attribute__((ext_vector_type(4)));

// ---------------- utility ----------------
__global__ void zero_kernel(int* __restrict__ p, int n) {
    int i = blockIdx.x * blockDim.x + threadIdx.x;
    if (i < n) p[i] = 0;
}

__global__ void count_kernel(const int4* __restrict__ dst4, int* __restrict__ indeg) {
    int e = blockIdx.x * blockDim.x + threadIdx.x;
    if (e < EE / 4) {
        int4 d = dst4[e];
        atomicAdd(&indeg[d.x], 1); atomicAdd(&indeg[d.y], 1);
        atomicAdd(&indeg[d.z], 1); atomicAdd(&indeg[d.w], 1);
    }
}

// ---------------- 3-phase multi-block exclusive scan (+dis fused in p1) ----------------
__global__ void scan_p1(const int* __restrict__ in, int* __restrict__ part, int n,
                        float* __restrict__ dis) {
    __shared__ int tile[256];
    int t = threadIdx.x;
    int i = blockIdx.x * 256 + t;
    int v = (i < n) ? in[i] : 0;
    tile[t] = v;
    if (i < n) dis[i] = 1.0f / sqrtf(1.0f + (float)v);
    __syncthreads();
    for (int o = 128; o > 0; o >>= 1) {
        if (t < o) tile[t] += tile[t + o];
        __syncthreads();
    }
    if (t == 0) part[blockIdx.x] = tile[0];
}

__global__ void scan_p2(int* __restrict__ part, int nb, int* __restrict__ off_end) {
    __shared__ int tile[256];
    int t = threadIdx.x;
    int v = (t < nb) ? part[t] : 0;
    tile[t] = v;
    __syncthreads();
    for (int o = 1; o < 256; o <<= 1) {
        int x = (t >= o) ? tile[t - o] : 0;
        __syncthreads();
        tile[t] += x;
        __syncthreads();
    }
    if (t < nb) part[t] = tile[t] - v;  // exclusive base per block
    if (t == 255) *off_end = tile[255];
}

__global__ void scan_p3(const int* __restrict__ in, const int* __restrict__ part,
                        int* __restrict__ out, int n) {
    __shared__ int tile[256];
    int t = threadIdx.x;
    int i = blockIdx.x * 256 + t;
    int v = (i < n) ? in[i] : 0;
    tile[t] = v;
    __syncthreads();
    for (int o = 1; o < 256; o <<= 1) {
        int x = (t >= o) ? tile[t - o] : 0;
        __syncthreads();
        tile[t] += x;
        __syncthreads();
    }
    if (i < n) out[i] = part[blockIdx.x] + tile[t] - v;
}

// scatter edges into dst-CSR (nbr only)
__global__ void scatter_kernel(const int4* __restrict__ src4, const int4* __restrict__ dst4,
                               const int* __restrict__ off, int* __restrict__ cur,
                               int* __restrict__ nbr) {
    int e = blockIdx.x * blockDim.x + threadIdx.x;
    if (e < EE / 4) {
        int4 s = src4[e], d = dst4[e];
        int p;
        p = atomicAdd(&cur[d.x], 1); nbr[off[d.x] + p] = s.x;
        p = atomicAdd(&cur[d.y], 1); nbr[off[d.y] + p] = s.y;
        p = atomicAdd(&cur[d.z], 1); nbr[off[d.z] + p] = s.z;
        p = atomicAdd(&cur[d.w], 1); nbr[off[d.w] + p] = s.w;
    }
}

// ---------------- fused weight transpose + f16 convert (W1, W2, Wa) ----------------
__global__ void transpose_w(const float* __restrict__ W1, __half* __restrict__ Wt1,
                            const float* __restrict__ W2, __half* __restrict__ Wt2,
                            const float* __restrict__ Wa, __half* __restrict__ WaT) {
    int i = blockIdx.x * 256 + threadIdx.x;
    if (i < DD * HH) {
        int k = i / HH, n = i % HH;
        Wt1[(size_t)n * DD + k] = __float2half(W1[i]);
    } else if (i < DD * HH + HH * HH) {
        int j = i - DD * HH;
        int k = j / HH, n = j % HH;
        Wt2[(size_t)n * HH + k] = __float2half(W2[j]);
    } else if (i < DD * HH + HH * HH + HH * KK) {
        int j = i - DD * HH - HH * HH;
        int k = j / KK, n = j % KK;
        WaT[n * HH + k] = __float2half(Wa[j]);
    }
}

// ---------------- strip-mined single-barrier MFMA GEMM ----------------
// C[M,256] = A[M,KDIM] @ Wt[256,KDIM]^T. Block = 32 rows x 256 cols, 4 waves
// (wave w covers cols w*64..w*64+63, rows 0..31 -> 2x4 mfma frags).
// FULL K-strip of A staged to f16 LDS once (one barrier), then pure
// MFMA + LDS reads with depth-1 B prefetch (B = 256KB, L2-resident).
// LDS row pad +8 halves (16B): bank rotation 4/row -> no extra conflicts.
template <typename TA, int KDIM>
__global__ __launch_bounds__(256) void mfma_gemm(const TA* __restrict__ A,
                                                 const __half* __restrict__ Bt,
                                                 __half* __restrict__ C, int M) {
    constexpr bool F32 = sizeof(TA) == 4;
    constexpr int SROW = KDIM + 8;       // halves
    constexpr int KI = KDIM / 32;
    constexpr int GROW = KDIM / 8;       // 16B granules per row
    constexpr int GPT = 32 * GROW / 256; // granules per thread
    __shared__ _Float16 As[32 * SROW];   // conv1 33.3KB, conv2 16.9KB

    int t = threadIdx.x;
    int wave = t >> 6, lane = t & 63, quad = lane >> 4, l16 = lane & 15;
    int row0 = blockIdx.x * 32;
    int coln = wave * 64;

    // stage all of A[row0..row0+32) x KDIM -> f16 LDS
#pragma unroll
    for (int g = 0; g < GPT; g++) {
        int gi = g * 256 + t;
        int row = gi / GROW, kc = gi % GROW;
        int grow = row0 + row;
        if (grow >= M) grow = M - 1;  // clamp: staged dup, never stored
        _Float16* dst = &As[row * SROW + kc * 8];
        if constexpr (F32) {
            const float* src = A + (size_t)grow * KDIM + kc * 8;
            float4 x0 = *(const float4*)src;
            float4 x1 = *(const float4*)(src + 4);
            _Float16 h[8];
            h[0] = (_Float16)x0.x; h[1] = (_Float16)x0.y;
            h[2] = (_Float16)x0.z; h[3] = (_Float16)x0.w;
            h[4] = (_Float16)x1.x; h[5] = (_Float16)x1.y;
            h[6] = (_Float16)x1.z; h[7] = (_Float16)x1.w;
            *(uint4*)dst = *(uint4*)h;
        } else {
            *(uint4*)dst = *(const uint4*)(A + (size_t)grow * KDIM + kc * 8);
        }
    }
    __syncthreads();

    const __half* bp[4];
#pragma unroll
    for (int ni = 0; ni < 4; ni++)
        bp[ni] = Bt + (size_t)(coln + ni * 16 + l16) * KDIM + quad * 8;

    f32x4 acc[2][4] = {};
    uint4 bcur[4], bnext[4];
#pragma unroll
    for (int ni = 0; ni < 4; ni++) bcur[ni] = *(const uint4*)bp[ni];

#pragma unroll
    for (int ki = 0; ki < KI; ki++) {
        if (ki + 1 < KI) {
#pragma unroll
            for (int ni = 0; ni < 4; ni++)
                bnext[ni] = *(const uint4*)(bp[ni] + (ki + 1) * 32);
        }
        half8_t af[2];
#pragma unroll
        for (int mi = 0; mi < 2; mi++)
            af[mi] = *(const half8_t*)&As[(mi * 16 + l16) * SROW + ki * 32 + quad * 8];
#pragma unroll
        for (int mi = 0; mi < 2; mi++)
#pragma unroll
            for (int ni = 0; ni < 4; ni++)
                acc[mi][ni] = __builtin_amdgcn_mfma_f32_16x16x32_f16(
                    af[mi], *(half8_t*)&bcur[ni], acc[mi][ni], 0, 0, 0);
        if (ki + 1 < KI) {
#pragma unroll
            for (int ni = 0; ni < 4; ni++) bcur[ni] = bnext[ni];
        }
    }

    // C write: reg r -> row=quad*4+r, col=l16
#pragma unroll
    for (int mi = 0; mi < 2; mi++) {
#pragma unroll
        for (int r = 0; r < 4; r++) {
            int rr = row0 + mi * 16 + quad * 4 + r;
            if (rr < M) {
#pragma unroll
                for (int ni = 0; ni < 4; ni++) {
                    C[(size_t)rr * HH + coln + ni * 16 + l16] =
                        __float2half(acc[mi][ni][r]);
                }
            }
        }
    }
}

// ---------------- aggregation + bias + SELU (+optional skip) ----------------
// Half-wave (32 lanes) per node, 8 ch/lane (16B loads), 8 nodes/block,
// x8 unroll with loads batched ahead of FMAs. Weights dis[s]*dis[n] on the fly.
__device__ inline void fma8(float* acc, uint4 raw, float w) {
    const __half2* h = (const __half2*)&raw;
#pragma unroll
    for (int i = 0; i < 4; i++) {
        float2 f = __half22float2(h[i]);
        acc[2 * i]     += w * f.x;
        acc[2 * i + 1] += w * f.y;
    }
}

__global__ __launch_bounds__(256) void agg_selu(const __half* __restrict__ T,
                                                const float* __restrict__ dis,
                                                const int* __restrict__ off,
                                                const int* __restrict__ nbr,
                                                const float* __restrict__ bias,
                                                const __half* skip, __half* out) {
    int t = threadIdx.x;
    int l32 = t & 31;
    int n = blockIdx.x * 8 + (t >> 5);
    int c = l32 * 8;
    float dn = dis[n];

    float acc[8];
#pragma unroll
    for (int i = 0; i < 8; i++) acc[i] = 0.f;
    fma8(acc, *(const uint4*)(T + (size_t)n * HH + c), dn * dn);  // self-loop

    int s0 = off[n], s1 = off[n + 1];
    for (int base = s0; base < s1; base += 32) {
        int cnt = min(32, s1 - base);
        int sidv = 0; float wv = 0.f;
        if (l32 < cnt) {
            sidv = nbr[base + l32];
            wv = dis[sidv] * dn;
        }
        int j = 0;
        for (; j + 8 <= cnt; j += 8) {
            int a0 = __shfl(sidv, j, 32),     a1 = __shfl(sidv, j + 1, 32);
            int a2 = __shfl(sidv, j + 2, 32), a3 = __shfl(sidv, j + 3, 32);
            int a4 = __shfl(sidv, j + 4, 32), a5 = __shfl(sidv, j + 5, 32);
            int a6 = __shfl(sidv, j + 6, 32), a7 = __shfl(sidv, j + 7, 32);
            float w0 = __shfl(wv, j, 32),     w1 = __shfl(wv, j + 1, 32);
            float w2 = __shfl(wv, j + 2, 32), w3 = __shfl(wv, j + 3, 32);
            float w4 = __shfl(wv, j + 4, 32), w5 = __shfl(wv, j + 5, 32);
            float w6 = __shfl(wv, j + 6, 32), w7 = __shfl(wv, j + 7, 32);
            uint4 r0 = *(const uint4*)(T + (size_t)a0 * HH + c);
            uint4 r1 = *(const uint4*)(T + (size_t)a1 * HH + c);
            uint4 r2 = *(const uint4*)(T + (size_t)a2 * HH + c);
            uint4 r3 = *(const uint4*)(T + (size_t)a3 * HH + c);
            uint4 r4 = *(const uint4*)(T + (size_t)a4 * HH + c);
            uint4 r5 = *(const uint4*)(T + (size_t)a5 * HH + c);
            uint4 r6 = *(const uint4*)(T + (size_t)a6 * HH + c);
            uint4 r7 = *(const uint4*)(T + (size_t)a7 * HH + c);
            fma8(acc, r0, w0); fma8(acc, r1, w1);
            fma8(acc, r2, w2); fma8(acc, r3, w3);
            fma8(acc, r4, w4); fma8(acc, r5, w5);
            fma8(acc, r6, w6); fma8(acc, r7, w7);
        }
        for (; j < cnt; j++) {
            int s = __shfl(sidv, j, 32);
            float w = __shfl(wv, j, 32);
            fma8(acc, *(const uint4*)(T + (size_t)s * HH + c), w);
        }
    }

    const float scale = 1.0507009873554805f;
    const float alpha = 1.6732632423543772f;
    float4 b0 = *(const float4*)(bias + c);
    float4 b1 = *(const float4*)(bias + c + 4);
    float bb[8] = {b0.x, b0.y, b0.z, b0.w, b1.x, b1.y, b1.z, b1.w};
    float sk8[8];
#pragma unroll
    for (int i = 0; i < 8; i++) sk8[i] = 0.f;
    if (skip) {
        uint4 raw = *(const uint4*)(skip + (size_t)n * HH + c);
        const __half2* h = (const __half2*)&raw;
#pragma unroll
        for (int i = 0; i < 4; i++) {
            float2 f = __half22float2(h[i]);
            sk8[2 * i] = f.x; sk8[2 * i + 1] = f.y;
        }
    }
    _Float16 res[8];
#pragma unroll
    for (int i = 0; i < 8; i++) {
        float v = acc[i] + bb[i];
        float r = v > 0.f ? scale * v : scale * alpha * expm1f(v);
        res[i] = (_Float16)(r + sk8[i]);
    }
    *(uint4*)(out + (size_t)n * HH + c) = *(uint4*)res;
}

// ---------------- assignment head via MFMA (cs + entropy partials) ----------------
__global__ __launch_bounds__(256) void assign_mfma(const __half* __restrict__ Hb,
                                                   const __half* __restrict__ WaT,
                                                   const float* __restrict__ ba,
                                                   float* __restrict__ out_assign,
                                                   __half* __restrict__ out_f16,
                                                   float* __restrict__ scal) {
    int t = threadIdx.x;
    int wave = t >> 6, lane = t & 63, quad = lane >> 4, l16 = lane & 15;
    int nb = blockIdx.x * 256 + wave * 64;

    f32x4 acc[4] = {};
    const __half* bp = WaT + l16 * HH + quad * 8;
    const __half* ap[4];
#pragma unroll
    for (int mi = 0; mi < 4; mi++) {
        int r = nb + mi * 16 + l16;
        if (r >= NN) r = NN - 1;
        ap[mi] = Hb + (size_t)r * HH + quad * 8;
    }
#pragma unroll
    for (int s = 0; s < 8; s++) {
        half8_t bf = *(const half8_t*)(bp + s * 32);
#pragma unroll
        for (int mi = 0; mi < 4; mi++) {
            half8_t af = *(const half8_t*)(ap[mi] + s * 32);
            acc[mi] = __builtin_amdgcn_mfma_f32_16x16x32_f16(af, bf, acc[mi], 0, 0, 0);
        }
    }

    float myb = ba[l16];
    float lcs = 0.f, lent = 0.f;
#pragma unroll
    for (int mi = 0; mi < 4; mi++) {
#pragma unroll
        for (int r = 0; r < 4; r++) {
            int node = nb + mi * 16 + quad * 4 + r;
            bool ok = node < NN;
            float logit = acc[mi][r] + myb;
            float mx = logit;
            for (int o = 1; o < 16; o <<= 1) mx = fmaxf(mx, __shfl_xor(mx, o, 16));
            float e = expf(logit - mx);
            float sum = e;
            for (int o = 1; o < 16; o <<= 1) sum += __shfl_xor(sum, o, 16);
            float a = e / sum;
            if (ok) {
                out_assign[(size_t)node * KK + l16] = a;
                out_f16[(size_t)node * KK + l16] = __float2half(a);
                lcs += a;
                lent += a * logf(a + 1e-8f);
            }
        }
    }
    lcs += __shfl_xor(lcs, 16); lcs += __shfl_xor(lcs, 32);
    for (int o = 32; o >= 1; o >>= 1) lent += __shfl_xor(lent, o);
    if (quad == 0) atomicAdd(&scal[l16], lcs);
    if (lane == 0) atomicAdd(&scal[33], lent);
}

// ---------------- fused trace(S^T A S) + dS over edges, f16 assignments ----------------
__device__ inline void loadrow16(const __half* p, float* v) {
    uint4 a0 = *(const uint4*)p, a1 = *(const uint4*)(p + 8);
    const __half2* h0 = (const __half2*)&a0;
    const __half2* h1 = (const __half2*)&a1;
#pragma unroll
    for (int i = 0; i < 4; i++) {
        float2 f = __half22float2(h0[i]);
        v[2 * i] = f.x; v[2 * i + 1] = f.y;
        float2 g = __half22float2(h1[i]);
        v[8 + 2 * i] = g.x; v[8 + 2 * i + 1] = g.y;
    }
}

__global__ __launch_bounds__(256) void edge_trace(const int4* __restrict__ src4,
                                                  const int4* __restrict__ dst4,
                                                  const __half* __restrict__ Ah,
                                                  float* __restrict__ scal,
                                                  float* __restrict__ dsacc) {
    int e = blockIdx.x * blockDim.x + threadIdx.x;
    int t = threadIdx.x;
    float p = 0.f;
    float ds[16];
#pragma unroll
    for (int k = 0; k < 16; k++) ds[k] = 0.f;
    if (e < EE / 4) {
        int4 s = src4[e], d = dst4[e];
        int ss[4] = {s.x, s.y, s.z, s.w};
        int dd[4] = {d.x, d.y, d.z, d.w};
#pragma unroll
        for (int j = 0; j < 4; j++) {
            float as_[16], ad_[16];
            loadrow16(Ah + (size_t)ss[j] * KK, as_);
            loadrow16(Ah + (size_t)dd[j] * KK, ad_);
#pragma unroll
            for (int k = 0; k < 16; k++) {
                p += as_[k] * ad_[k];
                ds[k] += as_[k];  // dS[k] = sum_e a_src[k] = degrees @ S
            }
        }
    }
    for (int o = 32; o >= 1; o >>= 1) p += __shfl_xor(p, o);
#pragma unroll
    for (int k = 0; k < 16; k++)
        for (int o = 32; o >= 1; o >>= 1) ds[k] += __shfl_xor(ds[k], o);

    __shared__ float sp;
    __shared__ float sds[16];
    if (t == 0) sp = 0.f;
    if (t < 16) sds[t] = 0.f;
    __syncthreads();
    if ((t & 63) == 0) {
        atomicAdd(&sp, p);
#pragma unroll
        for (int k = 0; k < 16; k++) atomicAdd(&sds[k], ds[k]);
    }
    __syncthreads();
    if (t == 0) atomicAdd(&scal[32], sp);
    if (t < 16) atomicAdd(&dsacc[t * 32], sds[t]);  // line-spread accumulators
}

// ---------------- pooled partial: pool_acc[k][d] += sum_n a[n][k]*emb[n][d] ----------------
#define PCH 125
__global__ __launch_bounds__(256) void pooled_partial(const float* __restrict__ emb,
                                                      const float* __restrict__ assign,
                                                      float* __restrict__ pool_acc) {
    int d = blockIdx.x * 256 + threadIdx.x;
    int c0 = blockIdx.y * PCH;
    float acc[KK];
#pragma unroll
    for (int k = 0; k < KK; k++) acc[k] = 0.f;
    __shared__ float sa[PCH * KK];  // 8 KB
    {
        const float4* srcv = (const float4*)(assign + (size_t)c0 * KK);
        float4* dstv = (float4*)sa;
        for (int i = threadIdx.x; i < PCH * KK / 4; i += 256) dstv[i] = srcv[i];
    }
    __syncthreads();
    for (int j = 0; j < PCH; j++) {
        float ev = emb[(size_t)(c0 + j) * DD + d];
#pragma unroll
        for (int k4 = 0; k4 < 4; k4++) {
            float4 s4 = *(const float4*)&sa[j * KK + k4 * 4];
            acc[k4 * 4 + 0] += s4.x * ev;
            acc[k4 * 4 + 1] += s4.y * ev;
            acc[k4 * 4 + 2] += s4.z * ev;
            acc[k4 * 4 + 3] += s4.w * ev;
        }
    }
#pragma unroll
    for (int k = 0; k < KK; k++) atomicAdd(&pool_acc[k * DD + d], acc[k]);
}

// ---------------- finalize: pooled normalize + scalar losses ----------------
__global__ void finalize(const float* __restrict__ pool_acc, const float* __restrict__ scal,
                         const float* __restrict__ dsacc, float* __restrict__ out) {
    int bx = blockIdx.x, t = threadIdx.x;
    if (bx < 32) {
        int i = bx * 256 + t;  // 0..8191
        int k = i / DD;
        out[800000 + i] = pool_acc[i] / (scal[k] + 1e-8f);
    } else if (t == 0) {
        float cs2 = 0.f, ds2 = 0.f;
        for (int k = 0; k < KK; k++) {
            cs2 += scal[k] * scal[k];
            float dk = dsacc[k * 32];
            ds2 += dk * dk;
        }
        float two_m = (float)EE;  // sum(degrees) == E, 2m == E
        float normalizer = ds2 / two_m;
        float trace = scal[32];
        float spectral = -(trace - (float)KK * normalizer) / two_m;
        float collapse = sqrtf(cs2) / (float)NN * 4.0f - 1.0f;  // sqrt(K)=4
        float entl = 0.1f * scal[33] / (float)NN;
        out[808192] = spectral;
        out[808193] = collapse;  // COLLAPSE_REG = 1.0
        out[808194] = spectral + collapse + entl;
        out[808195] = entl;
    }
}

extern "C" void kernel_launch(void* const* d_in, const int* in_sizes, int n_in,
                              void* d_out, int out_size, void* d_ws, size_t ws_size,
                              hipStream_t stream) {
    const float* emb = (const float*)d_in[0];
    const int* esrc  = (const int*)d_in[1];
    const int* edst  = (const int*)d_in[2];
    const float* W1  = (const float*)d_in[3];
    const float* b1  = (const float*)d_in[4];
    const float* W2  = (const float*)d_in[5];
    const float* b2  = (const float*)d_in[6];
    const float* Wa  = (const float*)d_in[7];
    const float* ba  = (const float*)d_in[8];
    float* out = (float*)d_out;

    // workspace layout (4B units unless noted) — total ~55.6 MB
    // zeroed prefix: indeg, cur, pool_acc, scal, dsacc, part = 109024 ints
    int* indeg      = (int*)d_ws;            // 50000
    int* cur        = indeg + 50000;         // 50000
    float* pool_acc = (float*)(cur + 50000); // 8192
    float* scal     = pool_acc + 8192;       // 64 (cs[16],-,trace@32,ent@33)
    float* dsacc    = scal + 64;             // 512 (dS[k] at k*32, line-spread)
    int* part       = (int*)(dsacc + 512);   // 256 (scan partials)
    int* off        = part + 256;            // 50001 (+pad to 50004)
    int* nbr        = off + 50004;           // 800000
    float* dis      = (float*)(nbr + 800000);// 50000
    __half* Wt1     = (__half*)(dis + 50000);    // 256*512 f16
    __half* Wt2     = Wt1 + 256 * 512;           // 256*256 f16
    __half* WaT     = Wt2 + 256 * 256;           // 16*256 f16
    __half* T       = WaT + 16 * 256;            // [NN][256] f16 (25.6 MB)
    __half* Hb      = T + (size_t)NN * HH;       // [NN][256] f16 (25.6 MB)
    __half* Ah      = T;  // f16 assignments alias T (dead after agg2)

    zero_kernel<<<dim3(426), 256, 0, stream>>>((int*)d_ws, 109024);
    count_kernel<<<dim3(782), 256, 0, stream>>>((const int4*)edst, indeg);

    // CSR offsets: 3-phase scan (+ dis in p1)
    scan_p1<<<dim3(NB_SCAN), 256, 0, stream>>>(indeg, part, NN, dis);
    scan_p2<<<dim3(1), 256, 0, stream>>>(part, NB_SCAN, off + NN);
    scan_p3<<<dim3(NB_SCAN), 256, 0, stream>>>(indeg, part, off, NN);
    scatter_kernel<<<dim3(782), 256, 0, stream>>>((const int4*)esrc, (const int4*)edst,
                                                  off, cur, nbr);

    // weights -> f16 transposed (fused: W1, W2, Wa)
    transpose_w<<<dim3(784), 256, 0, stream>>>(W1, Wt1, W2, Wt2, Wa, WaT);

    // conv1: T = emb @ W1 ; Hb = selu(Ahat*T + b1)
    mfma_gemm<float, DD><<<dim3(1563), 256, 0, stream>>>(emb, Wt1, T, NN);
    agg_selu<<<dim3(6250), 256, 0, stream>>>(T, dis, off, nbr, b1, nullptr, Hb);

    // conv2: T = Hb @ W2 ; Hb = selu(Ahat*T + b2) + Hb (skip, in place)
    mfma_gemm<__half, HH><<<dim3(1563), 256, 0, stream>>>(Hb, Wt2, T, NN);
    agg_selu<<<dim3(6250), 256, 0, stream>>>(T, dis, off, nbr, b2, Hb, Hb);

    // head: assignments -> d_out[0..800000) (+f16 copy), loss partials
    assign_mfma<<<dim3(196), 256, 0, stream>>>(Hb, WaT, ba, out, Ah, scal);
    edge_trace<<<dim3(782), 256, 0, stream>>>((const int4*)esrc, (const int4*)edst,
                                              Ah, scal, dsacc);
    pooled_partial<<<dim3(2, 400), 256, 0, stream>>>(emb, out, pool_acc);
    finalize<<<dim3(33), 256, 0, stream>>>(pool_acc, scal, dsacc, out);
}